// Round 5
// baseline (1723.094 us; speedup 1.0000x reference)
//
#include <hip/hip_runtime.h>
#include <hip/hip_bf16.h>

#define NUM_NODES 100000
#define EMBED_DIM 128
#define HIDDEN_DIM 512
#define NUM_EDGES 2000000
#define NUM_H 100000
#define LN_EPS 1e-5f
#define NCHUNK 98   // ceil(100000/1024)

// ---------------- workspace layout (int units) ----------------
#define OFF_COUNTS   0
#define OFF_CURSOR   100096
#define OFF_OFFSETS  200192
#define OFF_SORTED   300288
#define OFF_PARTIALS 2300288
#define OFF_BASES    2300416
#define OFF_W1HI     2300544   // 131072 bf16 = 65536 ints (256 KB)
#define OFF_W1LO     2366080   // contiguous after HI
// total: 2431616 ints ~ 9.3 MB

typedef __attribute__((ext_vector_type(8))) short bf16x8;
typedef __attribute__((ext_vector_type(4))) float f32x4;

__device__ __forceinline__ unsigned short f2bf(float x) {
    unsigned u = __float_as_uint(x);
    u += 0x7fff + ((u >> 16) & 1);          // RNE
    return (unsigned short)(u >> 16);
}
__device__ __forceinline__ float bf2f(unsigned short h) {
    return __uint_as_float(((unsigned)h) << 16);
}
// order-preserving float -> u32 map (for LDS atomicMax on unsigned)
__device__ __forceinline__ unsigned fmap(float f) {
    int i = __float_as_int(f);
    return (i >= 0) ? (((unsigned)i) | 0x80000000u) : ~((unsigned)i);
}
__device__ __forceinline__ float funmap(unsigned u) {
    unsigned i = (u & 0x80000000u) ? (u & 0x7FFFFFFFu) : ~u;
    return __int_as_float((int)i);
}

// ---------------- 0. pack W1 into MFMA B-fragment order, split hi/lo ----------------
// elem index e = (t*512 + n)*32 + g*8 + j ; value = W1[t*32 + g*8 + j][n]
__global__ __launch_bounds__(256) void pack_w1(const float* __restrict__ W1,
                                               unsigned short* __restrict__ hi,
                                               unsigned short* __restrict__ lo) {
    int e = blockIdx.x * 256 + threadIdx.x;           // 131072 total
    int t = e >> 14, rem = e & 16383;
    int n = rem >> 5, gj = rem & 31;
    int k = t * 32 + gj;
    float x = W1[k * HIDDEN_DIM + n];
    unsigned short h = f2bf(x);
    hi[e] = h;
    lo[e] = f2bf(x - bf2f(h));
}

// ---------------- 1. histogram (int4) ----------------
__global__ __launch_bounds__(256) void hist_kernel(const int4* __restrict__ eidx4,
                                                   int* __restrict__ counts) {
    int e = blockIdx.x * 256 + threadIdx.x;
    if (e < NUM_EDGES / 4) {
        int4 v = eidx4[e];
        atomicAdd(&counts[v.x], 1);
        atomicAdd(&counts[v.y], 1);
        atomicAdd(&counts[v.z], 1);
        atomicAdd(&counts[v.w], 1);
    }
}

// ---------------- 2a. per-chunk local exclusive scan ----------------
__global__ __launch_bounds__(1024) void scan_partial(const int* __restrict__ counts,
                                                     int* __restrict__ offsets,
                                                     int* __restrict__ partials) {
    __shared__ int wsum[16];
    __shared__ int woff[16];
    const int tid = threadIdx.x, b = blockIdx.x;
    const int warp = tid >> 6, lane = tid & 63;
    const int i = b * 1024 + tid;
    int v = (i < NUM_H) ? counts[i] : 0;
    int incl = v;
    #pragma unroll
    for (int off = 1; off < 64; off <<= 1) {
        int t = __shfl(incl, lane - off);
        if (lane >= off) incl += t;
    }
    if (lane == 63) wsum[warp] = incl;
    __syncthreads();
    if (tid < 16) {
        int s = wsum[tid], is = s;
        #pragma unroll
        for (int off = 1; off < 16; off <<= 1) {
            int t = __shfl(is, tid - off);
            if (tid >= off) is += t;
        }
        woff[tid] = is - s;
    }
    __syncthreads();
    if (i < NUM_H) offsets[i] = woff[warp] + incl - v;
    if (tid == 0) partials[b] = woff[15] + wsum[15];
}

// ---------------- 2b. scan the 98 chunk totals ----------------
__global__ __launch_bounds__(128) void scan_base(const int* __restrict__ partials,
                                                 int* __restrict__ bases) {
    __shared__ int t0;
    const int tid = threadIdx.x;
    const int lane = tid & 63, w = tid >> 6;
    int v = (tid < NCHUNK) ? partials[tid] : 0;
    int incl = v;
    #pragma unroll
    for (int off = 1; off < 64; off <<= 1) {
        int t = __shfl(incl, lane - off);
        if (lane >= off) incl += t;
    }
    if (tid == 63) t0 = incl;
    __syncthreads();
    bases[tid] = incl - v + (w ? t0 : 0);
}

// ---------------- 2c. add chunk base ----------------
__global__ __launch_bounds__(1024) void scan_add(int* __restrict__ offsets,
                                                 const int* __restrict__ bases) {
    const int i = blockIdx.x * 1024 + threadIdx.x;
    if (i < NUM_H) offsets[i] += bases[blockIdx.x];
    if (i == 0) offsets[NUM_H] = NUM_EDGES;
}

// ---------------- 3. scatter into CSR order, payload = nidx | localrow<<20 ----------------
__global__ __launch_bounds__(256) void scatter_kernel(const int4* __restrict__ nidx4,
                                                      const int4* __restrict__ eidx4,
                                                      const int* __restrict__ offsets,
                                                      int* __restrict__ cursor,
                                                      int* __restrict__ sorted) {
    int e = blockIdx.x * 256 + threadIdx.x;
    if (e < NUM_EDGES / 4) {
        int4 n = nidx4[e];
        int4 h = eidx4[e];
        {
            int pos = offsets[h.x] + atomicAdd(&cursor[h.x], 1);
            sorted[pos] = n.x | ((h.x & 31) << 20);
        }
        {
            int pos = offsets[h.y] + atomicAdd(&cursor[h.y], 1);
            sorted[pos] = n.y | ((h.y & 31) << 20);
        }
        {
            int pos = offsets[h.z] + atomicAdd(&cursor[h.z], 1);
            sorted[pos] = n.z | ((h.z & 31) << 20);
        }
        {
            int pos = offsets[h.w] + atomicAdd(&cursor[h.w], 1);
            sorted[pos] = n.w | ((h.w & 31) << 20);
        }
    }
}

// ---------------- 4. fused aggregate + MFMA MLP (M=32) ----------------
// Block = 256 threads (4 waves), 32 hyperedges/block.
// Stage 0: flat streaming loop over the block's contiguous CSR edge range,
//          8-deep software pipeline, mean/max accumulated in LDS via atomics.
// Stage 1: readback -> bf16 hi/lo A tile written in-place over the accumulators.
// Stage 2: 3-pass split-bf16 MFMA GEMM (2 row-tiles share B fragments).
// Stage 3: in-register LayerNorm + ReLU + GEMV.
__global__ __launch_bounds__(256) void fused_mlp_kernel(
        const float* __restrict__ embeds,
        const int* __restrict__ offsets,
        const int* __restrict__ sorted,
        const char* __restrict__ w1pack,   // hi @0, lo @+262144
        const float* __restrict__ b1,
        const float* __restrict__ gamma, const float* __restrict__ beta,
        const float* __restrict__ W2, const float* __restrict__ b2,
        float* __restrict__ out) {
    __shared__ __align__(16) float accum[8192];   // 32KB: sum[32][128] @0, maxu[32][128] @+16KB; A tile aliases after
    __shared__ float red_s[4][32];
    __shared__ float red_q[4][32];
    __shared__ float red_d[4][32];
    __shared__ int sOff[33];

    const int tid  = threadIdx.x;
    const int warp = tid >> 6;
    const int lane = tid & 63;
    const int m0   = blockIdx.x * 32;

    // ---- init: zero accumulators (0 bits = 0.0f sum and -inf-mapped max) ----
    #pragma unroll
    for (int i = 0; i < 8; ++i)
        ((f32x4*)accum)[tid + 256 * i] = (f32x4){0.f, 0.f, 0.f, 0.f};
    if (tid < 33) sOff[tid] = offsets[m0 + tid];
    __syncthreads();

    float*    sumb = accum;                       // [32][128]
    unsigned* maxb = (unsigned*)accum + 4096;     // [32][128]

    // ---- stage 0: streaming edge aggregation ----
    const int segBeg = sOff[0], segEnd = sOff[32];
    int p0 = segBeg + warp * 8;
    int cur[8];
    #pragma unroll
    for (int k = 0; k < 8; ++k) cur[k] = (p0 + k < segEnd) ? sorted[p0 + k] : -1;
    while (p0 < segEnd) {
        const int p1 = p0 + 32;
        int nxt[8];
        #pragma unroll
        for (int k = 0; k < 8; ++k) nxt[k] = (p1 + k < segEnd) ? sorted[p1 + k] : -1;
        float va[8], vb[8];
        #pragma unroll
        for (int k = 0; k < 8; ++k) {
            if (cur[k] >= 0) {
                const int node = cur[k] & 0xFFFFF;
                va[k] = embeds[node * EMBED_DIM + lane];
                vb[k] = embeds[node * EMBED_DIM + 64 + lane];
            }
        }
        #pragma unroll
        for (int k = 0; k < 8; ++k) {
            if (cur[k] >= 0) {
                const int row = cur[k] >> 20;
                atomicAdd(&sumb[row * 128 + lane], va[k]);
                atomicAdd(&sumb[row * 128 + 64 + lane], vb[k]);
                atomicMax(&maxb[row * 128 + lane], fmap(va[k]));
                atomicMax(&maxb[row * 128 + 64 + lane], fmap(vb[k]));
            }
        }
        #pragma unroll
        for (int k = 0; k < 8; ++k) cur[k] = nxt[k];
        p0 = p1;
    }
    __syncthreads();

    // ---- stage 1a: readback into registers ----
    float mA[8], mB[8], xA[8], xB[8];
    #pragma unroll
    for (int rr = 0; rr < 8; ++rr) {
        const int row = warp * 8 + rr;
        const int deg = sOff[row + 1] - sOff[row];
        const float inv = deg ? 1.f / (float)deg : 0.f;
        mA[rr] = sumb[row * 128 + lane] * inv;
        mB[rr] = sumb[row * 128 + 64 + lane] * inv;
        xA[rr] = deg ? funmap(maxb[row * 128 + lane]) : 0.f;
        xB[rr] = deg ? funmap(maxb[row * 128 + 64 + lane]) : 0.f;
    }
    __syncthreads();

    // ---- stage 1b: write swizzled bf16 hi/lo A tile in-place ----
    char* Ab = (char*)accum;   // A_hi [0,16K): row stride 512B; A_lo at +16384
    #pragma unroll
    for (int rr = 0; rr < 8; ++rr) {
        const int row = warp * 8 + rr;
        const unsigned swz = ((unsigned)(row & 7)) << 4;
        const float vals[4] = {mA[rr], mB[rr], xA[rr], xB[rr]};
        const int   ks[4]   = {lane, lane + 64, 128 + lane, 192 + lane};
        #pragma unroll
        for (int j = 0; j < 4; ++j) {
            const unsigned off = ((unsigned)(row * 512 + ks[j] * 2)) ^ swz;
            const unsigned short hbits = f2bf(vals[j]);
            *(unsigned short*)(Ab + off)         = hbits;
            *(unsigned short*)(Ab + 16384 + off) = f2bf(vals[j] - bf2f(hbits));
        }
    }
    __syncthreads();

    // ---- stage 2: z = h @ W1  (3-pass split-bf16 MFMA, 2 row-tiles) ----
    const int c = lane & 15, g = lane >> 4;
    const int wbase = warp * 128;              // this wave's 128-col slice
    f32x4 acc[2][8];
    #pragma unroll
    for (int rt = 0; rt < 2; ++rt)
        #pragma unroll
        for (int nt = 0; nt < 8; ++nt) acc[rt][nt] = (f32x4){0.f, 0.f, 0.f, 0.f};

    const char* bp = w1pack + (size_t)((wbase + c) * 64 + g * 16);
    const unsigned swzA = ((unsigned)(c & 7)) << 4;
    #pragma unroll
    for (int t = 0; t < 8; ++t) {
        const unsigned a0 = ((unsigned)(c * 512 + t * 64 + g * 16)) ^ swzA;
        bf16x8 ah0 = *(const bf16x8*)(Ab + a0);
        bf16x8 al0 = *(const bf16x8*)(Ab + 16384 + a0);
        bf16x8 ah1 = *(const bf16x8*)(Ab + 8192 + a0);          // rows c+16
        bf16x8 al1 = *(const bf16x8*)(Ab + 16384 + 8192 + a0);
        #pragma unroll
        for (int nt = 0; nt < 8; ++nt) {
            const char* p = bp + t * 32768 + nt * 1024;
            bf16x8 bh = *(const bf16x8*)p;
            bf16x8 bl = *(const bf16x8*)(p + 262144);
            acc[0][nt] = __builtin_amdgcn_mfma_f32_16x16x32_bf16(ah0, bh, acc[0][nt], 0, 0, 0);
            acc[0][nt] = __builtin_amdgcn_mfma_f32_16x16x32_bf16(al0, bh, acc[0][nt], 0, 0, 0);
            acc[0][nt] = __builtin_amdgcn_mfma_f32_16x16x32_bf16(ah0, bl, acc[0][nt], 0, 0, 0);
            acc[1][nt] = __builtin_amdgcn_mfma_f32_16x16x32_bf16(ah1, bh, acc[1][nt], 0, 0, 0);
            acc[1][nt] = __builtin_amdgcn_mfma_f32_16x16x32_bf16(al1, bh, acc[1][nt], 0, 0, 0);
            acc[1][nt] = __builtin_amdgcn_mfma_f32_16x16x32_bf16(ah1, bl, acc[1][nt], 0, 0, 0);
        }
    }

    // ---- stage 3: bias + LayerNorm + ReLU + GEMV, in-register ----
    // lane holds z[row = rt*16 + 4g+q][col = wbase + nt*16 + c]
    float b1v[8], gv[8], bev[8], w2v[8];
    #pragma unroll
    for (int nt = 0; nt < 8; ++nt) {
        const int col = wbase + nt * 16 + c;
        b1v[nt] = b1[col]; gv[nt] = gamma[col]; bev[nt] = beta[col]; w2v[nt] = W2[col];
    }
    float s[2][4], sq[2][4];
    #pragma unroll
    for (int rt = 0; rt < 2; ++rt)
        #pragma unroll
        for (int q = 0; q < 4; ++q) { s[rt][q] = 0.f; sq[rt][q] = 0.f; }
    #pragma unroll
    for (int rt = 0; rt < 2; ++rt)
        #pragma unroll
        for (int nt = 0; nt < 8; ++nt)
            #pragma unroll
            for (int q = 0; q < 4; ++q) {
                float z = acc[rt][nt][q] + b1v[nt];
                acc[rt][nt][q] = z;
                s[rt][q] += z; sq[rt][q] += z * z;
            }
    #pragma unroll
    for (int rt = 0; rt < 2; ++rt)
        #pragma unroll
        for (int q = 0; q < 4; ++q)
            #pragma unroll
            for (int off = 1; off < 16; off <<= 1) {
                s[rt][q]  += __shfl_xor(s[rt][q],  off);
                sq[rt][q] += __shfl_xor(sq[rt][q], off);
            }
    if (c == 0)
        #pragma unroll
        for (int rt = 0; rt < 2; ++rt)
            #pragma unroll
            for (int q = 0; q < 4; ++q) {
                red_s[warp][rt * 16 + g * 4 + q] = s[rt][q];
                red_q[warp][rt * 16 + g * 4 + q] = sq[rt][q];
            }
    __syncthreads();
    float d[2][4];
    #pragma unroll
    for (int rt = 0; rt < 2; ++rt)
        #pragma unroll
        for (int q = 0; q < 4; ++q) {
            const int row = rt * 16 + g * 4 + q;
            float S = red_s[0][row] + red_s[1][row] + red_s[2][row] + red_s[3][row];
            float Q = red_q[0][row] + red_q[1][row] + red_q[2][row] + red_q[3][row];
            float mu = S * (1.f / 512.f);
            float var = Q * (1.f / 512.f) - mu * mu;
            float rs = rsqrtf(var + LN_EPS);
            float acc_d = 0.f;
            #pragma unroll
            for (int nt = 0; nt < 8; ++nt) {
                float y = (acc[rt][nt][q] - mu) * rs * gv[nt] + bev[nt];
                y = fmaxf(y, 0.f);
                acc_d += y * w2v[nt];
            }
            d[rt][q] = acc_d;
        }
    #pragma unroll
    for (int rt = 0; rt < 2; ++rt)
        #pragma unroll
        for (int q = 0; q < 4; ++q)
            #pragma unroll
            for (int off = 1; off < 16; off <<= 1) d[rt][q] += __shfl_xor(d[rt][q], off);
    if (c == 0)
        #pragma unroll
        for (int rt = 0; rt < 2; ++rt)
            #pragma unroll
            for (int q = 0; q < 4; ++q) red_d[warp][rt * 16 + g * 4 + q] = d[rt][q];
    __syncthreads();
    if (tid < 32)
        out[m0 + tid] = red_d[0][tid] + red_d[1][tid] + red_d[2][tid] + red_d[3][tid] + b2[0];
}

extern "C" void kernel_launch(void* const* d_in, const int* in_sizes, int n_in,
                              void* d_out, int out_size, void* d_ws, size_t ws_size,
                              hipStream_t stream) {
    const float* embeds = (const float*)d_in[0];
    const int*   hidx   = (const int*)d_in[1];
    const float* W1     = (const float*)d_in[2];
    const float* b1     = (const float*)d_in[3];
    const float* gamma  = (const float*)d_in[4];
    const float* beta   = (const float*)d_in[5];
    const float* W2     = (const float*)d_in[6];
    const float* b2     = (const float*)d_in[7];
    float*       out    = (float*)d_out;

    int* ws       = (int*)d_ws;
    int* counts   = ws + OFF_COUNTS;
    int* cursor   = ws + OFF_CURSOR;
    int* offsets  = ws + OFF_OFFSETS;
    int* sorted   = ws + OFF_SORTED;
    int* partials = ws + OFF_PARTIALS;
    int* bases    = ws + OFF_BASES;
    unsigned short* w1hi = (unsigned short*)(ws + OFF_W1HI);
    unsigned short* w1lo = (unsigned short*)(ws + OFF_W1LO);

    const int* nidx = hidx;
    const int* eidx = hidx + NUM_EDGES;

    hipMemsetAsync(d_ws, 0, (size_t)OFF_OFFSETS * sizeof(int), stream);

    pack_w1<<<512, 256, 0, stream>>>(W1, w1hi, w1lo);
    const int eb4 = (NUM_EDGES / 4 + 255) / 256;
    hist_kernel<<<eb4, 256, 0, stream>>>((const int4*)eidx, counts);
    scan_partial<<<NCHUNK, 1024, 0, stream>>>(counts, offsets, partials);
    scan_base<<<1, 128, 0, stream>>>(partials, bases);
    scan_add<<<NCHUNK, 1024, 0, stream>>>(offsets, bases);
    scatter_kernel<<<eb4, 256, 0, stream>>>((const int4*)nidx, (const int4*)eidx,
                                            offsets, cursor, sorted);
    fused_mlp_kernel<<<NUM_H / 32, 256, 0, stream>>>(embeds, offsets, sorted,
                                                     (const char*)(ws + OFF_W1HI),
                                                     b1, gamma, beta, W2, b2, out);
}

// Round 7
// 638.703 us; speedup vs baseline: 2.6978x; 2.6978x over previous
//
#include <hip/hip_runtime.h>
#include <hip/hip_bf16.h>

#define NUM_NODES 100000
#define EMBED_DIM 128
#define HIDDEN_DIM 512
#define NUM_EDGES 2000000
#define NUM_H 100000
#define LN_EPS 1e-5f
#define NCHUNK 98   // ceil(100000/1024)

// ---------------- workspace layout (int units) ----------------
#define OFF_COUNTS   0
#define OFF_CURSOR   100096
#define OFF_OFFSETS  200192
#define OFF_SORTED   300288
#define OFF_PARTIALS 2300288
#define OFF_BASES    2300416   // 128 ints
#define OFF_W1HI     2300544   // hi: 131072 bf16 = 256 KB
#define OFF_W1LO     2366080   // lo: contiguous after
// total: 2431616 ints ~ 9.3 MB

typedef __attribute__((ext_vector_type(8))) short bf16x8;
typedef __attribute__((ext_vector_type(4))) float f32x4;

__device__ __forceinline__ unsigned short f2bf(float x) {
    unsigned u = __float_as_uint(x);
    u += 0x7fff + ((u >> 16) & 1);          // RNE
    return (unsigned short)(u >> 16);
}
__device__ __forceinline__ float bf2f(unsigned short h) {
    return __uint_as_float(((unsigned)h) << 16);
}

// ---------------- 0. pack W1 into MFMA B-fragment order, split hi/lo ----------------
// elem index e = (t*512 + n)*32 + g*8 + j ; value = W1[t*32 + g*8 + j][n]
__global__ __launch_bounds__(256) void pack_w1(const float* __restrict__ W1,
                                               unsigned short* __restrict__ hi,
                                               unsigned short* __restrict__ lo) {
    int e = blockIdx.x * 256 + threadIdx.x;           // 131072 total
    int t = e >> 14, rem = e & 16383;
    int n = rem >> 5, gj = rem & 31;
    int k = t * 32 + gj;
    float x = W1[k * HIDDEN_DIM + n];
    unsigned short h = f2bf(x);
    hi[e] = h;
    lo[e] = f2bf(x - bf2f(h));
}

// ---------------- 1. histogram (int4) ----------------
__global__ __launch_bounds__(256) void hist_kernel(const int4* __restrict__ eidx4,
                                                   int* __restrict__ counts) {
    int e = blockIdx.x * 256 + threadIdx.x;
    if (e < NUM_EDGES / 4) {
        int4 v = eidx4[e];
        atomicAdd(&counts[v.x], 1);
        atomicAdd(&counts[v.y], 1);
        atomicAdd(&counts[v.z], 1);
        atomicAdd(&counts[v.w], 1);
    }
}

// ---------------- 2a. per-chunk local exclusive scan ----------------
__global__ __launch_bounds__(1024) void scan_partial(const int* __restrict__ counts,
                                                     int* __restrict__ offsets,
                                                     int* __restrict__ partials) {
    __shared__ int wsum[16];
    __shared__ int woff[16];
    const int tid = threadIdx.x, b = blockIdx.x;
    const int warp = tid >> 6, lane = tid & 63;
    const int i = b * 1024 + tid;
    int v = (i < NUM_H) ? counts[i] : 0;
    int incl = v;
    #pragma unroll
    for (int off = 1; off < 64; off <<= 1) {
        int t = __shfl(incl, lane - off);
        if (lane >= off) incl += t;
    }
    if (lane == 63) wsum[warp] = incl;
    __syncthreads();
    if (tid < 16) {
        int s = wsum[tid], is = s;
        #pragma unroll
        for (int off = 1; off < 16; off <<= 1) {
            int t = __shfl(is, tid - off);
            if (tid >= off) is += t;
        }
        woff[tid] = is - s;
    }
    __syncthreads();
    if (i < NUM_H) offsets[i] = woff[warp] + incl - v;   // chunk-local exclusive
    if (tid == 0) partials[b] = woff[15] + wsum[15];
}

// ---------------- 2b. scan the 98 chunk totals -> global chunk bases ----------------
__global__ __launch_bounds__(128) void scan_base(const int* __restrict__ partials,
                                                 int* __restrict__ bases) {
    __shared__ int t0;
    const int tid = threadIdx.x;
    const int lane = tid & 63, w = tid >> 6;
    int v = (tid < NCHUNK) ? partials[tid] : 0;
    int incl = v;
    #pragma unroll
    for (int off = 1; off < 64; off <<= 1) {
        int t = __shfl(incl, lane - off);
        if (lane >= off) incl += t;
    }
    if (tid == 63) t0 = incl;
    __syncthreads();
    bases[tid] = incl - v + (w ? t0 : 0);
}

// ---------------- 3. scatter into CSR order (bases folded in) ----------------
__global__ __launch_bounds__(256) void scatter_kernel(const int4* __restrict__ nidx4,
                                                      const int4* __restrict__ eidx4,
                                                      const int* __restrict__ offsets,
                                                      const int* __restrict__ bases,
                                                      int* __restrict__ cursor,
                                                      int* __restrict__ sorted) {
    int e = blockIdx.x * 256 + threadIdx.x;
    if (e < NUM_EDGES / 4) {
        int4 n = nidx4[e];
        int4 h = eidx4[e];
        {
            int pos = offsets[h.x] + bases[h.x >> 10] + atomicAdd(&cursor[h.x], 1);
            sorted[pos] = n.x;
        }
        {
            int pos = offsets[h.y] + bases[h.y >> 10] + atomicAdd(&cursor[h.y], 1);
            sorted[pos] = n.y;
        }
        {
            int pos = offsets[h.z] + bases[h.z >> 10] + atomicAdd(&cursor[h.z], 1);
            sorted[pos] = n.z;
        }
        {
            int pos = offsets[h.w] + bases[h.w >> 10] + atomicAdd(&cursor[h.w], 1);
            sorted[pos] = n.w;
        }
    }
}

// ---------------- 4. fused aggregate + MFMA MLP (M=32, register aggregation) ----------------
// Block = 256 threads (4 waves), 32 hyperedges/block; wave owns 8 rows.
// Stage 0: per row, 8-edge groups with 2-level pipeline (idx +2 groups ahead,
//          values +1 group ahead); mean/max in registers -> swizzled bf16 hi/lo A tile.
// Stage 1: 3-pass split-bf16 MFMA GEMM (2 row-tiles share B; B pipelined 1 step).
// Stage 2: in-register LayerNorm + ReLU + GEMV.
__global__ __launch_bounds__(256) void fused_mlp_kernel(
        const float* __restrict__ embeds,
        const int* __restrict__ offsets,
        const int* __restrict__ bases,
        const int* __restrict__ sorted,
        const char* __restrict__ w1pack,   // hi @0, lo @+262144
        const float* __restrict__ b1,
        const float* __restrict__ gamma, const float* __restrict__ beta,
        const float* __restrict__ W2, const float* __restrict__ b2,
        float* __restrict__ out) {
    __shared__ __align__(16) char Ab[32768];      // A_hi [32][512B] @0 ; A_lo @+16384
    __shared__ float red_s[4][32];
    __shared__ float red_q[4][32];
    __shared__ float red_d[4][32];
    __shared__ int sOff[33];

    const int tid  = threadIdx.x;
    const int warp = tid >> 6;
    const int lane = tid & 63;
    const int m0   = blockIdx.x * 32;

    if (tid < 33) {
        const int idx = m0 + tid;
        sOff[tid] = (idx >= NUM_H) ? NUM_EDGES : offsets[idx] + bases[idx >> 10];
    }
    __syncthreads();

    // ---- stage 0: per-row pipelined gather + aggregate ----
    for (int rr = 0; rr < 8; ++rr) {
        const int row = warp * 8 + rr;
        const int beg = sOff[row], end = sOff[row + 1];
        float2 sum = {0.f, 0.f};
        float2 mx  = {-3.402823466e38f, -3.402823466e38f};
        int n0[8], n1[8];
        float2 v0[8], v1[8];
        #pragma unroll
        for (int k = 0; k < 8; ++k) n0[k] = (beg + k < end) ? sorted[beg + k] : -1;
        #pragma unroll
        for (int k = 0; k < 8; ++k) n1[k] = (beg + 8 + k < end) ? sorted[beg + 8 + k] : -1;
        #pragma unroll
        for (int k = 0; k < 8; ++k)
            if (n0[k] >= 0) v0[k] = *(const float2*)&embeds[(size_t)n0[k] * EMBED_DIM + lane * 2];
        for (int i = beg; i < end; i += 8) {
            int n2[8];
            #pragma unroll
            for (int k = 0; k < 8; ++k) n2[k] = (i + 16 + k < end) ? sorted[i + 16 + k] : -1;
            #pragma unroll
            for (int k = 0; k < 8; ++k)
                if (n1[k] >= 0) v1[k] = *(const float2*)&embeds[(size_t)n1[k] * EMBED_DIM + lane * 2];
            #pragma unroll
            for (int k = 0; k < 8; ++k)
                if (n0[k] >= 0) {
                    sum.x += v0[k].x; sum.y += v0[k].y;
                    mx.x = fmaxf(mx.x, v0[k].x); mx.y = fmaxf(mx.y, v0[k].y);
                }
            #pragma unroll
            for (int k = 0; k < 8; ++k) { n0[k] = n1[k]; n1[k] = n2[k]; v0[k] = v1[k]; }
        }
        const int deg = end - beg;
        const float inv = deg ? 1.f / (float)deg : 0.f;
        float2 mean = {sum.x * inv, sum.y * inv};
        if (!deg) { mx.x = 0.f; mx.y = 0.f; }
        const unsigned swz = ((unsigned)(row & 7)) << 4;
        const unsigned bm  = ((unsigned)(row * 512 + lane * 4)) ^ swz;        // k = 2l,2l+1
        const unsigned bx  = ((unsigned)(row * 512 + 256 + lane * 4)) ^ swz;  // k = 128+2l
        unsigned short h0 = f2bf(mean.x), h1 = f2bf(mean.y);
        *(unsigned*)(Ab + bm)         = (unsigned)h0 | ((unsigned)h1 << 16);
        *(unsigned*)(Ab + 16384 + bm) = (unsigned)f2bf(mean.x - bf2f(h0)) |
                                        ((unsigned)f2bf(mean.y - bf2f(h1)) << 16);
        unsigned short g0 = f2bf(mx.x), g1 = f2bf(mx.y);
        *(unsigned*)(Ab + bx)         = (unsigned)g0 | ((unsigned)g1 << 16);
        *(unsigned*)(Ab + 16384 + bx) = (unsigned)f2bf(mx.x - bf2f(g0)) |
                                        ((unsigned)f2bf(mx.y - bf2f(g1)) << 16);
    }
    __syncthreads();

    // ---- stage 1: z = h @ W1  (3-pass split-bf16 MFMA, 2 row-tiles, B pipelined) ----
    const int c = lane & 15, g = lane >> 4;
    const int wbase = warp * 128;              // this wave's 128-col slice
    f32x4 acc[2][8];
    #pragma unroll
    for (int rt = 0; rt < 2; ++rt)
        #pragma unroll
        for (int nt = 0; nt < 8; ++nt) acc[rt][nt] = (f32x4){0.f, 0.f, 0.f, 0.f};

    const char* bbase = w1pack + (size_t)((wbase + c) * 64 + g * 16);
    const unsigned swzA = ((unsigned)(c & 7)) << 4;
    bf16x8 bh = *(const bf16x8*)bbase;
    bf16x8 bl = *(const bf16x8*)(bbase + 262144);
    #pragma unroll
    for (int t = 0; t < 8; ++t) {
        const unsigned a0 = ((unsigned)(c * 512 + t * 64 + g * 16)) ^ swzA;
        bf16x8 ah0 = *(const bf16x8*)(Ab + a0);
        bf16x8 al0 = *(const bf16x8*)(Ab + 16384 + a0);
        bf16x8 ah1 = *(const bf16x8*)(Ab + 8192 + a0);          // rows c+16
        bf16x8 al1 = *(const bf16x8*)(Ab + 16384 + 8192 + a0);
        #pragma unroll
        for (int nt = 0; nt < 8; ++nt) {
            const char* pn = (nt < 7) ? bbase + t * 32768 + (nt + 1) * 1024
                           : (t < 7) ? bbase + (t + 1) * 32768
                                     : bbase;                    // clamped dummy
            bf16x8 bh_n = *(const bf16x8*)pn;
            bf16x8 bl_n = *(const bf16x8*)(pn + 262144);
            acc[0][nt] = __builtin_amdgcn_mfma_f32_16x16x32_bf16(ah0, bh, acc[0][nt], 0, 0, 0);
            acc[1][nt] = __builtin_amdgcn_mfma_f32_16x16x32_bf16(ah1, bh, acc[1][nt], 0, 0, 0);
            acc[0][nt] = __builtin_amdgcn_mfma_f32_16x16x32_bf16(al0, bh, acc[0][nt], 0, 0, 0);
            acc[1][nt] = __builtin_amdgcn_mfma_f32_16x16x32_bf16(al1, bh, acc[1][nt], 0, 0, 0);
            acc[0][nt] = __builtin_amdgcn_mfma_f32_16x16x32_bf16(ah0, bl, acc[0][nt], 0, 0, 0);
            acc[1][nt] = __builtin_amdgcn_mfma_f32_16x16x32_bf16(ah1, bl, acc[1][nt], 0, 0, 0);
            bh = bh_n; bl = bl_n;
        }
    }

    // ---- stage 2: bias + LayerNorm + ReLU + GEMV, in-register ----
    // lane holds z[row = rt*16 + 4g+q][col = wbase + nt*16 + c]
    float b1v[8], gv[8], bev[8], w2v[8];
    #pragma unroll
    for (int nt = 0; nt < 8; ++nt) {
        const int col = wbase + nt * 16 + c;
        b1v[nt] = b1[col]; gv[nt] = gamma[col]; bev[nt] = beta[col]; w2v[nt] = W2[col];
    }
    float s[2][4], sq[2][4];
    #pragma unroll
    for (int rt = 0; rt < 2; ++rt)
        #pragma unroll
        for (int q = 0; q < 4; ++q) { s[rt][q] = 0.f; sq[rt][q] = 0.f; }
    #pragma unroll
    for (int rt = 0; rt < 2; ++rt)
        #pragma unroll
        for (int nt = 0; nt < 8; ++nt)
            #pragma unroll
            for (int q = 0; q < 4; ++q) {
                float z = acc[rt][nt][q] + b1v[nt];
                acc[rt][nt][q] = z;
                s[rt][q] += z; sq[rt][q] += z * z;
            }
    #pragma unroll
    for (int rt = 0; rt < 2; ++rt)
        #pragma unroll
        for (int q = 0; q < 4; ++q)
            #pragma unroll
            for (int off = 1; off < 16; off <<= 1) {
                s[rt][q]  += __shfl_xor(s[rt][q],  off);
                sq[rt][q] += __shfl_xor(sq[rt][q], off);
            }
    if (c == 0)
        #pragma unroll
        for (int rt = 0; rt < 2; ++rt)
            #pragma unroll
            for (int q = 0; q < 4; ++q) {
                red_s[warp][rt * 16 + g * 4 + q] = s[rt][q];
                red_q[warp][rt * 16 + g * 4 + q] = sq[rt][q];
            }
    __syncthreads();
    float d[2][4];
    #pragma unroll
    for (int rt = 0; rt < 2; ++rt)
        #pragma unroll
        for (int q = 0; q < 4; ++q) {
            const int row = rt * 16 + g * 4 + q;
            float S = red_s[0][row] + red_s[1][row] + red_s[2][row] + red_s[3][row];
            float Q = red_q[0][row] + red_q[1][row] + red_q[2][row] + red_q[3][row];
            float mu = S * (1.f / 512.f);
            float var = Q * (1.f / 512.f) - mu * mu;
            float rs = rsqrtf(var + LN_EPS);
            float acc_d = 0.f;
            #pragma unroll
            for (int nt = 0; nt < 8; ++nt) {
                float y = (acc[rt][nt][q] - mu) * rs * gv[nt] + bev[nt];
                y = fmaxf(y, 0.f);
                acc_d += y * w2v[nt];
            }
            d[rt][q] = acc_d;
        }
    #pragma unroll
    for (int rt = 0; rt < 2; ++rt)
        #pragma unroll
        for (int q = 0; q < 4; ++q)
            #pragma unroll
            for (int off = 1; off < 16; off <<= 1) d[rt][q] += __shfl_xor(d[rt][q], off);
    if (c == 0)
        #pragma unroll
        for (int rt = 0; rt < 2; ++rt)
            #pragma unroll
            for (int q = 0; q < 4; ++q) red_d[warp][rt * 16 + g * 4 + q] = d[rt][q];
    __syncthreads();
    if (tid < 32)
        out[m0 + tid] = red_d[0][tid] + red_d[1][tid] + red_d[2][tid] + red_d[3][tid] + b2[0];
}

extern "C" void kernel_launch(void* const* d_in, const int* in_sizes, int n_in,
                              void* d_out, int out_size, void* d_ws, size_t ws_size,
                              hipStream_t stream) {
    const float* embeds = (const float*)d_in[0];
    const int*   hidx   = (const int*)d_in[1];
    const float* W1     = (const float*)d_in[2];
    const float* b1     = (const float*)d_in[3];
    const float* gamma  = (const float*)d_in[4];
    const float* beta   = (const float*)d_in[5];
    const float* W2     = (const float*)d_in[6];
    const float* b2     = (const float*)d_in[7];
    float*       out    = (float*)d_out;

    int* ws       = (int*)d_ws;
    int* counts   = ws + OFF_COUNTS;
    int* cursor   = ws + OFF_CURSOR;
    int* offsets  = ws + OFF_OFFSETS;
    int* sorted   = ws + OFF_SORTED;
    int* partials = ws + OFF_PARTIALS;
    int* bases    = ws + OFF_BASES;
    unsigned short* w1hi = (unsigned short*)(ws + OFF_W1HI);
    unsigned short* w1lo = (unsigned short*)(ws + OFF_W1LO);

    const int* nidx = hidx;
    const int* eidx = hidx + NUM_EDGES;

    hipMemsetAsync(d_ws, 0, (size_t)OFF_OFFSETS * sizeof(int), stream);

    pack_w1<<<512, 256, 0, stream>>>(W1, w1hi, w1lo);
    const int eb4 = (NUM_EDGES / 4 + 255) / 256;
    hist_kernel<<<eb4, 256, 0, stream>>>((const int4*)eidx, counts);
    scan_partial<<<NCHUNK, 1024, 0, stream>>>(counts, offsets, partials);
    scan_base<<<1, 128, 0, stream>>>(partials, bases);
    scatter_kernel<<<eb4, 256, 0, stream>>>((const int4*)nidx, (const int4*)eidx,
                                            offsets, bases, cursor, sorted);
    fused_mlp_kernel<<<NUM_H / 32, 256, 0, stream>>>(embeds, offsets, bases, sorted,
                                                     (const char*)(ws + OFF_W1HI),
                                                     b1, gamma, beta, W2, b2, out);
}